// Round 9
// baseline (233.536 us; speedup 1.0000x reference)
//
#include <hip/hip_runtime.h>

using f16   = _Float16;
using f16x2 = __attribute__((ext_vector_type(2))) f16;
using f16x4 = __attribute__((ext_vector_type(4))) f16;
using f16x8 = __attribute__((ext_vector_type(8))) f16;
using f32x4 = __attribute__((ext_vector_type(4))) float;

#define L_ 4096
#define C_ 512

static __device__ __forceinline__ float fast_exp2(float x) {
#if __has_builtin(__builtin_amdgcn_exp2f)
  return __builtin_amdgcn_exp2f(x);
#else
  float r; asm("v_exp_f32 %0, %1" : "=v"(r) : "v"(x)); return r;
#endif
}

// packed f32->f16 (RTZ) convert; bit-cast __fp16 vec -> _Float16 vec
static __device__ __forceinline__ f16x2 pk2(float a, float b) {
  return __builtin_bit_cast(f16x2, __builtin_amdgcn_cvt_pkrtz(a, b));
}

// workspace layout (bytes), all offsets 256-aligned
#define WS_SC    0u          // float2[4096*16]   sin/cos table      524288
#define WS_WQKV  524288u     // f16[768*512]                         786432
#define WS_WO    1310720u    // f16[512*512]                         524288
#define WS_Q     1835008u    // f16[2][8][4096][64]                  8388608
#define WS_K     10223616u   // f16[2][2][4096][64]                  2097152
#define WS_VT    12320768u   // f16[2][2][64][4096]  (transposed V)  2097152
#define WS_ATT   14417920u   // f16[2][4096][512]                    8388608
#define WS_OP    22806528u   // f32[2][2][8][4096][64] O partials    33554432
#define WS_LS    56360960u   // f32[2][2][8][4096]    lsum partials  524288
#define WS_END   56885248u

// ---------------------------------------------------------------- prep
__global__ __launch_bounds__(256) void prep_kernel(
    const float* __restrict__ Wq, const float* __restrict__ Wkv,
    const float* __restrict__ Wo,
    f16* __restrict__ wqkv, f16* __restrict__ wo16, float2* __restrict__ sc) {
  int t = blockIdx.x * 256 + threadIdx.x;
  if (t < 98304) {                 // 768*512 f16, 4 per thread
    int idx = t * 4;
    float4 v = (idx < 262144) ? *(const float4*)(Wq + idx)
                              : *(const float4*)(Wkv + (idx - 262144));
    f16x4 o = {(f16)v.x, (f16)v.y, (f16)v.z, (f16)v.w};
    *(f16x4*)(wqkv + idx) = o;
  } else if (t < 163840) {         // 512*512 f16
    int idx = (t - 98304) * 4;
    float4 v = *(const float4*)(Wo + idx);
    f16x4 o = {(f16)v.x, (f16)v.y, (f16)v.z, (f16)v.w};
    *(f16x4*)(wo16 + idx) = o;
  } else if (t < 229376) {         // 4096*16 sin/cos entries
    int e = t - 163840;
    int l = e >> 4, p = e & 15;
    float invf = exp2f(-(float)p * (13.287712379549449f / 16.0f));
    float ang = (float)l * invf;
    sc[e] = make_float2(sinf(ang), cosf(ang));
  }
}

// ---------------------------------------------------------------- QKV + RoPE
__global__ __launch_bounds__(256) void qkv_kernel(
    const float* __restrict__ x, const f16* __restrict__ wqkv,
    const float2* __restrict__ sc,
    f16* __restrict__ Qo, f16* __restrict__ Ko, f16* __restrict__ Vto) {
  int bid = blockIdx.x;
  int b   = bid / 384;
  int rem = bid % 384;
  int ot  = rem >> 7;       // 0..2
  int lt  = rem & 127;      // 0..127
  int wave = threadIdx.x >> 6, lane = threadIdx.x & 63;
  int lo = lane & 15, hi = lane >> 4;
  int obase = ot * 256 + wave * 64;
  int lbase = lt * 32;
  const float* xb = x + (size_t)b * C_ * L_;

  f32x4 acc[4][2] = {};
  for (int kc = 0; kc < 512; kc += 32) {
    f16x8 aw[4];
#pragma unroll
    for (int oc = 0; oc < 4; ++oc)
      aw[oc] = *(const f16x8*)(wqkv + (obase + oc * 16 + lo) * 512 + kc + hi * 8);
#pragma unroll
    for (int lc = 0; lc < 2; ++lc) {
      f16x8 bx;
#pragma unroll
      for (int i = 0; i < 8; ++i)
        bx[i] = (f16)xb[(size_t)(kc + hi * 8 + i) * L_ + lbase + lc * 16 + lo];
#pragma unroll
      for (int oc = 0; oc < 4; ++oc)
        acc[oc][lc] = __builtin_amdgcn_mfma_f32_16x16x32_f16(aw[oc], bx, acc[oc][lc], 0, 0, 0);
    }
  }

  bool is_q = obase < 512;
  int  og   = obase - 512;
  int  kvh  = is_q ? 0 : (og >> 7);
  bool is_v = (!is_q) && ((og & 127) == 64);
  int  h    = obase >> 6;
  const float QSCALE = 0.125f * 1.44269504088896340736f;

#pragma unroll
  for (int oc = 0; oc < 4; ++oc) {
#pragma unroll
    for (int lc = 0; lc < 2; ++lc) {
      f32x4 v = acc[oc][lc];
      int l = lbase + lc * 16 + lo;
      int d = oc * 16 + hi * 4;
      if (!is_v && oc < 2) {           // rotary on d<32 for q and k
        int p0 = d >> 1;
        float2 s0 = sc[l * 16 + p0];
        float2 s1 = sc[l * 16 + p0 + 1];
        float a0 = v[0], a1 = v[1], a2 = v[2], a3 = v[3];
        v[0] = a0 * s0.y - a1 * s0.x;
        v[1] = a1 * s0.y + a0 * s0.x;
        v[2] = a2 * s1.y - a3 * s1.x;
        v[3] = a3 * s1.y + a2 * s1.x;
      }
      if (is_q) {
        f16x4 st = {(f16)(v[0] * QSCALE), (f16)(v[1] * QSCALE),
                    (f16)(v[2] * QSCALE), (f16)(v[3] * QSCALE)};
        *(f16x4*)(Qo + (((size_t)b * 8 + h) * L_ + l) * 64 + d) = st;
      } else if (!is_v) {
        f16x4 st = {(f16)v[0], (f16)v[1], (f16)v[2], (f16)v[3]};
        *(f16x4*)(Ko + (((size_t)b * 2 + kvh) * L_ + l) * 64 + d) = st;
      } else {
#pragma unroll
        for (int i = 0; i < 4; ++i)
          Vto[(((size_t)b * 2 + kvh) * 64 + d + i) * L_ + l] = (f16)v[i];
      }
    }
  }
}

// ---------------------------------------------------------------- flash attention
// Block = 8 waves x 16 q rows = 128 q rows, 512 threads.
// KSPLIT: grid 1024, each block does 2048 keys (32 chunks), writes unnormalized
// O-partial (f32) + lsum to ws; combine kernel adds halves & normalizes.
// (fixed-max softmax => partials combine by plain addition)
// !KSPLIT: grid 512, 64 chunks, writes normalized att f16 directly.
template <bool KSPLIT>
__global__ __launch_bounds__(512, 8) void attn_kernel(
    const f16* __restrict__ Qi, const f16* __restrict__ Ki,
    const f16* __restrict__ Vti, f16* __restrict__ att,
    float* __restrict__ opart, float* __restrict__ lsews) {
  __shared__ __align__(16) char smem[2][16384];
  int bid  = blockIdx.x;
  int half = KSPLIT ? (bid >> 9) : 0;
  int rem9 = KSPLIT ? (bid & 511) : bid;
  int b   = rem9 >> 8;
  int rem = rem9 & 255;
  int h   = rem >> 5;
  int qt  = rem & 31;
  int tid  = threadIdx.x;
  int wave = tid >> 6, lane = tid & 63;
  int lo = lane & 15, hi = lane >> 4;
  int kvh = h >> 2;
  const f16*  Qp   = Qi + ((size_t)(b * 8 + h) * L_) * 64;
  const char* Ksrc = (const char*)(Ki  + ((size_t)(b * 2 + kvh)) * L_ * 64)
                     + (size_t)half * 262144;                     // +2048 keys
  const char* Vsrc = (const char*)(Vti + ((size_t)(b * 2 + kvh)) * 64 * L_)
                     + (size_t)half * 4096;                       // +2048 cols

  int lqb = qt * 128 + wave * 16;
  f16x8 qf[2];
#pragma unroll
  for (int hf = 0; hf < 2; ++hf)
    qf[hf] = *(const f16x8*)(Qp + (size_t)(lqb + lo) * 64 + hf * 32 + hi * 8);

  // staging: 512 threads, one 16B K-chunk + one 16B V-chunk each (8KB tiles)
  int c0 = tid;
  int r0 = c0 >> 3, m0 = c0 & 7;
  int cb0 = m0 << 4;
  int dstK0 = r0 * 128 + (cb0 ^ ((r0 & 7) << 4));
  int ca0 = (m0 >> 2) * 64 + ((2 * m0) & 3) * 16 + ((m0 >> 1) & 1) * 8;
  int dstV0a = r0 * 128 + (ca0 ^ ((r0 & 7) << 4));
  int dstV0b = r0 * 128 + ((ca0 + 16) ^ ((r0 & 7) << 4));

  f16x8 sK0, sV0;
#define STAGE_LOAD(t) do {                                            \
    sK0 = *(const f16x8*)(Ksrc + (size_t)(t) * 8192 + c0 * 16);       \
    sV0 = *(const f16x8*)(Vsrc + (size_t)r0 * 8192 + (t) * 128 + cb0);\
  } while (0)
#define STAGE_WRITE(base_) do {                                       \
    char* kb_ = (char*)(base_);                                       \
    *(f16x8*)(kb_ + dstK0) = sK0;                                     \
    *(f16x4*)(kb_ + 8192 + dstV0a) = __builtin_shufflevector(sV0, sV0, 0, 1, 2, 3); \
    *(f16x4*)(kb_ + 8192 + dstV0b) = __builtin_shufflevector(sV0, sV0, 4, 5, 6, 7); \
  } while (0)

  f32x4 oacc[4] = {};
  f32x4 lse = {};                           // ones-row MFMA accumulator
  const f16x4 ones = {(f16)1.f, (f16)1.f, (f16)1.f, (f16)1.f};
  int swz = (lo & 7) << 4;

#define COMPUTE(buf_) do {                                                          \
    const char* kb = (const char*)(buf_);                                           \
    const char* vb = kb + 8192;                                                     \
    f32x4 s[4] = {};                                                                \
    __builtin_amdgcn_s_setprio(1);                                                  \
    _Pragma("unroll")                                                               \
    for (int j = 0; j < 4; ++j) {                                                   \
      f16x8 ka0 = *(const f16x8*)(kb + (j * 16 + lo) * 128 + ((hi * 16) ^ swz));    \
      f16x8 ka1 = *(const f16x8*)(kb + (j * 16 + lo) * 128 + ((64 + hi * 16) ^ swz));\
      s[j] = __builtin_amdgcn_mfma_f32_16x16x32_f16(ka0, qf[0], s[j], 0, 0, 0);     \
      s[j] = __builtin_amdgcn_mfma_f32_16x16x32_f16(ka1, qf[1], s[j], 0, 0, 0);     \
    }                                                                               \
    __builtin_amdgcn_s_setprio(0);                                                  \
    f16x4 pf[4];                                                                    \
    _Pragma("unroll")                                                               \
    for (int j = 0; j < 4; ++j) {                                                   \
      f16x2 p01 = pk2(fast_exp2(s[j][0]), fast_exp2(s[j][1]));                      \
      f16x2 p23 = pk2(fast_exp2(s[j][2]), fast_exp2(s[j][3]));                      \
      pf[j] = __builtin_shufflevector(p01, p23, 0, 1, 2, 3);                        \
    }                                                                               \
    __builtin_amdgcn_s_setprio(1);                                                  \
    _Pragma("unroll")                                                               \
    for (int dc = 0; dc < 4; ++dc) {                                                \
      _Pragma("unroll")                                                             \
      for (int jp = 0; jp < 2; ++jp) {                                              \
        f16x8 vv = *(const f16x8*)(vb + (dc * 16 + lo) * 128 + ((jp * 64 + hi * 16) ^ swz)); \
        f16x4 va0 = __builtin_shufflevector(vv, vv, 0, 1, 2, 3);                    \
        f16x4 va1 = __builtin_shufflevector(vv, vv, 4, 5, 6, 7);                    \
        oacc[dc] = __builtin_amdgcn_mfma_f32_16x16x16f16(va0, pf[2 * jp], oacc[dc], 0, 0, 0); \
        oacc[dc] = __builtin_amdgcn_mfma_f32_16x16x16f16(va1, pf[2 * jp + 1], oacc[dc], 0, 0, 0); \
      }                                                                             \
    }                                                                               \
    _Pragma("unroll")                                                               \
    for (int j = 0; j < 4; ++j)                                                     \
      lse = __builtin_amdgcn_mfma_f32_16x16x16f16(ones, pf[j], lse, 0, 0, 0);       \
    __builtin_amdgcn_s_setprio(0);                                                  \
  } while (0)

  const int NT = KSPLIT ? 32 : 64;
  STAGE_LOAD(0);
  STAGE_WRITE(smem[0]);
  __syncthreads();

  for (int t = 0; t < NT; t += 2) {
    STAGE_LOAD(t + 1);                 // t+1 <= NT-1 always valid
    COMPUTE(smem[0]);
    STAGE_WRITE(smem[1]);
    __syncthreads();
    if (t + 2 < NT) STAGE_LOAD(t + 2);
    COMPUTE(smem[1]);
    if (t + 2 < NT) STAGE_WRITE(smem[0]);
    __syncthreads();
  }

  int lq = lqb + lo;
  if constexpr (KSPLIT) {
    size_t obase = ((((size_t)half * 2 + b) * 8 + h) * L_ + lq) * 64;
#pragma unroll
    for (int dc = 0; dc < 4; ++dc)
      *(f32x4*)(opart + obase + dc * 16 + hi * 4) = oacc[dc];
    if (hi == 0)
      lsews[(((size_t)half * 2 + b) * 8 + h) * L_ + lq] = lse[0];
  } else {
    float inv = 1.f / lse[0];
#pragma unroll
    for (int dc = 0; dc < 4; ++dc) {
      f16x4 st;
#pragma unroll
      for (int i = 0; i < 4; ++i) st[i] = (f16)(oacc[dc][i] * inv);
      *(f16x4*)(att + ((size_t)b * L_ + lq) * 512 + h * 64 + dc * 16 + hi * 4) = st;
    }
  }
#undef STAGE_LOAD
#undef STAGE_WRITE
#undef COMPUTE
}

// ---------------------------------------------------------------- combine halves
__global__ __launch_bounds__(256) void combine_kernel(
    const float* __restrict__ opart, const float* __restrict__ lsews,
    f16* __restrict__ att) {
  int t = blockIdx.x * 256 + threadIdx.x;     // 2*8*4096*16 = 1048576 threads
  int d4 = t & 15;
  int lq = (t >> 4) & 4095;
  int h  = (t >> 16) & 7;
  int b  = t >> 19;
  const size_t HS = (size_t)2 * 8 * 4096 * 64;     // opart half stride (floats)
  size_t base  = (((size_t)b * 8 + h) * 4096 + lq) * 64 + d4 * 4;
  size_t lbase = ((size_t)b * 8 + h) * 4096 + lq;
  f32x4 o0 = *(const f32x4*)(opart + base);
  f32x4 o1 = *(const f32x4*)(opart + HS + base);
  float inv = 1.f / (lsews[lbase] + lsews[(size_t)2 * 8 * 4096 + lbase]);
  f16x4 st;
#pragma unroll
  for (int i = 0; i < 4; ++i) st[i] = (f16)((o0[i] + o1[i]) * inv);
  *(f16x4*)(att + ((size_t)b * 4096 + lq) * 512 + h * 64 + d4 * 4) = st;
}

// ---------------------------------------------------------------- output projection
__global__ __launch_bounds__(256) void oproj_kernel(
    const f16* __restrict__ att, const f16* __restrict__ wo16,
    float* __restrict__ out) {
  int bid = blockIdx.x;
  int b   = bid / 256;
  int rem = bid % 256;
  int ct  = rem >> 7;
  int lt  = rem & 127;
  int wave = threadIdx.x >> 6, lane = threadIdx.x & 63;
  int lo = lane & 15, hi = lane >> 4;
  int cobase = ct * 256 + wave * 64;
  int lbase  = lt * 32;
  const f16* ab = att + (size_t)b * L_ * 512;

  f32x4 acc[4][2] = {};
  for (int kc = 0; kc < 512; kc += 32) {
    f16x8 aw[4];
#pragma unroll
    for (int cc = 0; cc < 4; ++cc)
      aw[cc] = *(const f16x8*)(wo16 + (cobase + cc * 16 + lo) * 512 + kc + hi * 8);
#pragma unroll
    for (int lc = 0; lc < 2; ++lc) {
      f16x8 bx = *(const f16x8*)(ab + (size_t)(lbase + lc * 16 + lo) * 512 + kc + hi * 8);
#pragma unroll
      for (int cc = 0; cc < 4; ++cc)
        acc[cc][lc] = __builtin_amdgcn_mfma_f32_16x16x32_f16(aw[cc], bx, acc[cc][lc], 0, 0, 0);
    }
  }
  float* ob = out + (size_t)b * C_ * L_;
#pragma unroll
  for (int cc = 0; cc < 4; ++cc)
#pragma unroll
    for (int lc = 0; lc < 2; ++lc) {
      int l = lbase + lc * 16 + lo;
#pragma unroll
      for (int i = 0; i < 4; ++i) {
        int co = cobase + cc * 16 + hi * 4 + i;
        ob[(size_t)co * L_ + l] = acc[cc][lc][i];
      }
    }
}

// ---------------------------------------------------------------- launch
extern "C" void kernel_launch(void* const* d_in, const int* in_sizes, int n_in,
                              void* d_out, int out_size, void* d_ws, size_t ws_size,
                              hipStream_t stream) {
  const float* x   = (const float*)d_in[0];
  const float* Wq  = (const float*)d_in[1];
  const float* Wkv = (const float*)d_in[2];
  const float* Wo  = (const float*)d_in[3];
  char* ws = (char*)d_ws;
  float2* sc  = (float2*)(ws + WS_SC);
  f16* wqkv   = (f16*)(ws + WS_WQKV);
  f16* wo16   = (f16*)(ws + WS_WO);
  f16* Qb     = (f16*)(ws + WS_Q);
  f16* Kb     = (f16*)(ws + WS_K);
  f16* Vtb    = (f16*)(ws + WS_VT);
  f16* attb   = (f16*)(ws + WS_ATT);
  float* opb  = (float*)(ws + WS_OP);
  float* lsb  = (float*)(ws + WS_LS);

  prep_kernel<<<1024, 256, 0, stream>>>(Wq, Wkv, Wo, wqkv, wo16, sc);
  qkv_kernel<<<768, 256, 0, stream>>>(x, wqkv, sc, Qb, Kb, Vtb);
  if (ws_size >= (size_t)WS_END) {
    attn_kernel<true><<<1024, 512, 0, stream>>>(Qb, Kb, Vtb, attb, opb, lsb);
    combine_kernel<<<4096, 256, 0, stream>>>(opb, lsb, attb);
  } else {
    attn_kernel<false><<<512, 512, 0, stream>>>(Qb, Kb, Vtb, attb, opb, lsb);
  }
  oproj_kernel<<<512, 256, 0, stream>>>(attb, wo16, (float*)d_out);
}

// Round 10
// 174.329 us; speedup vs baseline: 1.3396x; 1.3396x over previous
//
#include <hip/hip_runtime.h>

using f16   = _Float16;
using f16x2 = __attribute__((ext_vector_type(2))) f16;
using f16x4 = __attribute__((ext_vector_type(4))) f16;
using f16x8 = __attribute__((ext_vector_type(8))) f16;
using f32x4 = __attribute__((ext_vector_type(4))) float;

#define L_ 4096
#define C_ 512

static __device__ __forceinline__ float fast_exp2(float x) {
#if __has_builtin(__builtin_amdgcn_exp2f)
  return __builtin_amdgcn_exp2f(x);
#else
  float r; asm("v_exp_f32 %0, %1" : "=v"(r) : "v"(x)); return r;
#endif
}

// packed f32->f16 (RTZ) convert; bit-cast __fp16 vec -> _Float16 vec
static __device__ __forceinline__ f16x2 pk2(float a, float b) {
  return __builtin_bit_cast(f16x2, __builtin_amdgcn_cvt_pkrtz(a, b));
}

// workspace layout (bytes), all offsets 256-aligned
#define WS_SC    0u          // float2[4096*16]   sin/cos table      524288
#define WS_WQKV  524288u     // f16[768*512]                         786432
#define WS_WO    1310720u    // f16[512*512]                         524288
#define WS_Q     1835008u    // f16[2][8][4096][64]                  8388608
#define WS_K     10223616u   // f16[2][2][4096][64]                  2097152
#define WS_VT    12320768u   // f16[2][2][64][4096]  (transposed V)  2097152
#define WS_ATT   14417920u   // f16[2][4096][512]                    8388608
#define WS_OP    22806528u   // f32[2][2][8][4096][64] O partials    33554432
#define WS_LS    56360960u   // f32[2][2][8][4096]    lsum partials  524288
#define WS_END   56885248u

// ---------------------------------------------------------------- prep
__global__ __launch_bounds__(256) void prep_kernel(
    const float* __restrict__ Wq, const float* __restrict__ Wkv,
    const float* __restrict__ Wo,
    f16* __restrict__ wqkv, f16* __restrict__ wo16, float2* __restrict__ sc) {
  int t = blockIdx.x * 256 + threadIdx.x;
  if (t < 98304) {                 // 768*512 f16, 4 per thread
    int idx = t * 4;
    float4 v = (idx < 262144) ? *(const float4*)(Wq + idx)
                              : *(const float4*)(Wkv + (idx - 262144));
    f16x4 o = {(f16)v.x, (f16)v.y, (f16)v.z, (f16)v.w};
    *(f16x4*)(wqkv + idx) = o;
  } else if (t < 163840) {         // 512*512 f16
    int idx = (t - 98304) * 4;
    float4 v = *(const float4*)(Wo + idx);
    f16x4 o = {(f16)v.x, (f16)v.y, (f16)v.z, (f16)v.w};
    *(f16x4*)(wo16 + idx) = o;
  } else if (t < 229376) {         // 4096*16 sin/cos entries
    int e = t - 163840;
    int l = e >> 4, p = e & 15;
    float invf = exp2f(-(float)p * (13.287712379549449f / 16.0f));
    float ang = (float)l * invf;
    sc[e] = make_float2(sinf(ang), cosf(ang));
  }
}

// ---------------------------------------------------------------- QKV + RoPE
__global__ __launch_bounds__(256) void qkv_kernel(
    const float* __restrict__ x, const f16* __restrict__ wqkv,
    const float2* __restrict__ sc,
    f16* __restrict__ Qo, f16* __restrict__ Ko, f16* __restrict__ Vto) {
  int bid = blockIdx.x;
  int b   = bid / 384;
  int rem = bid % 384;
  int ot  = rem >> 7;       // 0..2
  int lt  = rem & 127;      // 0..127
  int wave = threadIdx.x >> 6, lane = threadIdx.x & 63;
  int lo = lane & 15, hi = lane >> 4;
  int obase = ot * 256 + wave * 64;
  int lbase = lt * 32;
  const float* xb = x + (size_t)b * C_ * L_;

  f32x4 acc[4][2] = {};
  for (int kc = 0; kc < 512; kc += 32) {
    f16x8 aw[4];
#pragma unroll
    for (int oc = 0; oc < 4; ++oc)
      aw[oc] = *(const f16x8*)(wqkv + (obase + oc * 16 + lo) * 512 + kc + hi * 8);
#pragma unroll
    for (int lc = 0; lc < 2; ++lc) {
      f16x8 bx;
#pragma unroll
      for (int i = 0; i < 8; ++i)
        bx[i] = (f16)xb[(size_t)(kc + hi * 8 + i) * L_ + lbase + lc * 16 + lo];
#pragma unroll
      for (int oc = 0; oc < 4; ++oc)
        acc[oc][lc] = __builtin_amdgcn_mfma_f32_16x16x32_f16(aw[oc], bx, acc[oc][lc], 0, 0, 0);
    }
  }

  bool is_q = obase < 512;
  int  og   = obase - 512;
  int  kvh  = is_q ? 0 : (og >> 7);
  bool is_v = (!is_q) && ((og & 127) == 64);
  int  h    = obase >> 6;
  const float QSCALE = 0.125f * 1.44269504088896340736f;

#pragma unroll
  for (int oc = 0; oc < 4; ++oc) {
#pragma unroll
    for (int lc = 0; lc < 2; ++lc) {
      f32x4 v = acc[oc][lc];
      int l = lbase + lc * 16 + lo;
      int d = oc * 16 + hi * 4;
      if (!is_v && oc < 2) {           // rotary on d<32 for q and k
        int p0 = d >> 1;
        float2 s0 = sc[l * 16 + p0];
        float2 s1 = sc[l * 16 + p0 + 1];
        float a0 = v[0], a1 = v[1], a2 = v[2], a3 = v[3];
        v[0] = a0 * s0.y - a1 * s0.x;
        v[1] = a1 * s0.y + a0 * s0.x;
        v[2] = a2 * s1.y - a3 * s1.x;
        v[3] = a3 * s1.y + a2 * s1.x;
      }
      if (is_q) {
        f16x4 st = {(f16)(v[0] * QSCALE), (f16)(v[1] * QSCALE),
                    (f16)(v[2] * QSCALE), (f16)(v[3] * QSCALE)};
        *(f16x4*)(Qo + (((size_t)b * 8 + h) * L_ + l) * 64 + d) = st;
      } else if (!is_v) {
        f16x4 st = {(f16)v[0], (f16)v[1], (f16)v[2], (f16)v[3]};
        *(f16x4*)(Ko + (((size_t)b * 2 + kvh) * L_ + l) * 64 + d) = st;
      } else {
#pragma unroll
        for (int i = 0; i < 4; ++i)
          Vto[(((size_t)b * 2 + kvh) * 64 + d + i) * L_ + l] = (f16)v[i];
      }
    }
  }
}

// ---------------------------------------------------------------- flash attention
// Block = 8 waves x 16 q rows = 128 q rows, 512 threads.
// KSPLIT: grid 1024, each block does 2048 keys (32 chunks), writes unnormalized
// O-partial (f32) + lsum to ws; combine kernel adds halves & normalizes.
// (fixed-max softmax => partials combine by plain addition)
// NOTE: plain __launch_bounds__(512) — the (512,8) variant capped VGPR at 32
// and spilled ~500MB of scratch to HBM (round-9 post-mortem).
template <bool KSPLIT>
__global__ __launch_bounds__(512) void attn_kernel(
    const f16* __restrict__ Qi, const f16* __restrict__ Ki,
    const f16* __restrict__ Vti, f16* __restrict__ att,
    float* __restrict__ opart, float* __restrict__ lsews) {
  __shared__ __align__(16) char smem[2][16384];
  int bid  = blockIdx.x;
  int half = KSPLIT ? (bid >> 9) : 0;
  int rem9 = KSPLIT ? (bid & 511) : bid;
  int b   = rem9 >> 8;
  int rem = rem9 & 255;
  int h   = rem >> 5;
  int qt  = rem & 31;
  int tid  = threadIdx.x;
  int wave = tid >> 6, lane = tid & 63;
  int lo = lane & 15, hi = lane >> 4;
  int kvh = h >> 2;
  const f16*  Qp   = Qi + ((size_t)(b * 8 + h) * L_) * 64;
  const char* Ksrc = (const char*)(Ki  + ((size_t)(b * 2 + kvh)) * L_ * 64)
                     + (size_t)half * 262144;                     // +2048 keys
  const char* Vsrc = (const char*)(Vti + ((size_t)(b * 2 + kvh)) * 64 * L_)
                     + (size_t)half * 4096;                       // +2048 cols

  int lqb = qt * 128 + wave * 16;
  f16x8 qf[2];
#pragma unroll
  for (int hf = 0; hf < 2; ++hf)
    qf[hf] = *(const f16x8*)(Qp + (size_t)(lqb + lo) * 64 + hf * 32 + hi * 8);

  // staging: 512 threads, one 16B K-chunk + one 16B V-chunk each (8KB tiles)
  int c0 = tid;
  int r0 = c0 >> 3, m0 = c0 & 7;
  int cb0 = m0 << 4;
  int dstK0 = r0 * 128 + (cb0 ^ ((r0 & 7) << 4));
  int ca0 = (m0 >> 2) * 64 + ((2 * m0) & 3) * 16 + ((m0 >> 1) & 1) * 8;
  int dstV0a = r0 * 128 + (ca0 ^ ((r0 & 7) << 4));
  int dstV0b = r0 * 128 + ((ca0 + 16) ^ ((r0 & 7) << 4));

  f16x8 sK0, sV0;
#define STAGE_LOAD(t) do {                                            \
    sK0 = *(const f16x8*)(Ksrc + (size_t)(t) * 8192 + c0 * 16);       \
    sV0 = *(const f16x8*)(Vsrc + (size_t)r0 * 8192 + (t) * 128 + cb0);\
  } while (0)
#define STAGE_WRITE(base_) do {                                       \
    char* kb_ = (char*)(base_);                                       \
    *(f16x8*)(kb_ + dstK0) = sK0;                                     \
    *(f16x4*)(kb_ + 8192 + dstV0a) = __builtin_shufflevector(sV0, sV0, 0, 1, 2, 3); \
    *(f16x4*)(kb_ + 8192 + dstV0b) = __builtin_shufflevector(sV0, sV0, 4, 5, 6, 7); \
  } while (0)

  f32x4 oacc[4] = {};
  f32x4 lse = {};                           // ones-row MFMA accumulator
  const f16x4 ones = {(f16)1.f, (f16)1.f, (f16)1.f, (f16)1.f};
  int swz = (lo & 7) << 4;

#define COMPUTE(buf_) do {                                                          \
    const char* kb = (const char*)(buf_);                                           \
    const char* vb = kb + 8192;                                                     \
    f32x4 s[4] = {};                                                                \
    __builtin_amdgcn_s_setprio(1);                                                  \
    _Pragma("unroll")                                                               \
    for (int j = 0; j < 4; ++j) {                                                   \
      f16x8 ka0 = *(const f16x8*)(kb + (j * 16 + lo) * 128 + ((hi * 16) ^ swz));    \
      f16x8 ka1 = *(const f16x8*)(kb + (j * 16 + lo) * 128 + ((64 + hi * 16) ^ swz));\
      s[j] = __builtin_amdgcn_mfma_f32_16x16x32_f16(ka0, qf[0], s[j], 0, 0, 0);     \
      s[j] = __builtin_amdgcn_mfma_f32_16x16x32_f16(ka1, qf[1], s[j], 0, 0, 0);     \
    }                                                                               \
    __builtin_amdgcn_s_setprio(0);                                                  \
    f16x4 pf[4];                                                                    \
    _Pragma("unroll")                                                               \
    for (int j = 0; j < 4; ++j) {                                                   \
      f16x2 p01 = pk2(fast_exp2(s[j][0]), fast_exp2(s[j][1]));                      \
      f16x2 p23 = pk2(fast_exp2(s[j][2]), fast_exp2(s[j][3]));                      \
      pf[j] = __builtin_shufflevector(p01, p23, 0, 1, 2, 3);                        \
    }                                                                               \
    __builtin_amdgcn_s_setprio(1);                                                  \
    _Pragma("unroll")                                                               \
    for (int dc = 0; dc < 4; ++dc) {                                                \
      _Pragma("unroll")                                                             \
      for (int jp = 0; jp < 2; ++jp) {                                              \
        f16x8 vv = *(const f16x8*)(vb + (dc * 16 + lo) * 128 + ((jp * 64 + hi * 16) ^ swz)); \
        f16x4 va0 = __builtin_shufflevector(vv, vv, 0, 1, 2, 3);                    \
        f16x4 va1 = __builtin_shufflevector(vv, vv, 4, 5, 6, 7);                    \
        oacc[dc] = __builtin_amdgcn_mfma_f32_16x16x16f16(va0, pf[2 * jp], oacc[dc], 0, 0, 0); \
        oacc[dc] = __builtin_amdgcn_mfma_f32_16x16x16f16(va1, pf[2 * jp + 1], oacc[dc], 0, 0, 0); \
      }                                                                             \
    }                                                                               \
    _Pragma("unroll")                                                               \
    for (int j = 0; j < 4; ++j)                                                     \
      lse = __builtin_amdgcn_mfma_f32_16x16x16f16(ones, pf[j], lse, 0, 0, 0);       \
    __builtin_amdgcn_s_setprio(0);                                                  \
  } while (0)

  const int NT = KSPLIT ? 32 : 64;
  STAGE_LOAD(0);
  STAGE_WRITE(smem[0]);
  __syncthreads();

  for (int t = 0; t < NT; t += 2) {
    STAGE_LOAD(t + 1);                 // t+1 <= NT-1 always valid
    COMPUTE(smem[0]);
    STAGE_WRITE(smem[1]);
    __syncthreads();
    if (t + 2 < NT) STAGE_LOAD(t + 2);
    COMPUTE(smem[1]);
    if (t + 2 < NT) STAGE_WRITE(smem[0]);
    __syncthreads();
  }

  int lq = lqb + lo;
  if constexpr (KSPLIT) {
    size_t obase = ((((size_t)half * 2 + b) * 8 + h) * L_ + lq) * 64;
#pragma unroll
    for (int dc = 0; dc < 4; ++dc)
      *(f32x4*)(opart + obase + dc * 16 + hi * 4) = oacc[dc];
    if (hi == 0)
      lsews[(((size_t)half * 2 + b) * 8 + h) * L_ + lq] = lse[0];
  } else {
    float inv = 1.f / lse[0];
#pragma unroll
    for (int dc = 0; dc < 4; ++dc) {
      f16x4 st;
#pragma unroll
      for (int i = 0; i < 4; ++i) st[i] = (f16)(oacc[dc][i] * inv);
      *(f16x4*)(att + ((size_t)b * L_ + lq) * 512 + h * 64 + dc * 16 + hi * 4) = st;
    }
  }
#undef STAGE_LOAD
#undef STAGE_WRITE
#undef COMPUTE
}

// ---------------------------------------------------------------- combine halves
__global__ __launch_bounds__(256) void combine_kernel(
    const float* __restrict__ opart, const float* __restrict__ lsews,
    f16* __restrict__ att) {
  int t = blockIdx.x * 256 + threadIdx.x;     // 2*8*4096*16 = 1048576 threads
  int d4 = t & 15;
  int lq = (t >> 4) & 4095;
  int h  = (t >> 16) & 7;
  int b  = t >> 19;
  const size_t HS = (size_t)2 * 8 * 4096 * 64;     // opart half stride (floats)
  size_t base  = (((size_t)b * 8 + h) * 4096 + lq) * 64 + d4 * 4;
  size_t lbase = ((size_t)b * 8 + h) * 4096 + lq;
  f32x4 o0 = *(const f32x4*)(opart + base);
  f32x4 o1 = *(const f32x4*)(opart + HS + base);
  float inv = 1.f / (lsews[lbase] + lsews[(size_t)2 * 8 * 4096 + lbase]);
  f16x4 st;
#pragma unroll
  for (int i = 0; i < 4; ++i) st[i] = (f16)((o0[i] + o1[i]) * inv);
  *(f16x4*)(att + ((size_t)b * 4096 + lq) * 512 + h * 64 + d4 * 4) = st;
}

// ---------------------------------------------------------------- output projection
__global__ __launch_bounds__(256) void oproj_kernel(
    const f16* __restrict__ att, const f16* __restrict__ wo16,
    float* __restrict__ out) {
  int bid = blockIdx.x;
  int b   = bid / 256;
  int rem = bid % 256;
  int ct  = rem >> 7;
  int lt  = rem & 127;
  int wave = threadIdx.x >> 6, lane = threadIdx.x & 63;
  int lo = lane & 15, hi = lane >> 4;
  int cobase = ct * 256 + wave * 64;
  int lbase  = lt * 32;
  const f16* ab = att + (size_t)b * L_ * 512;

  f32x4 acc[4][2] = {};
  for (int kc = 0; kc < 512; kc += 32) {
    f16x8 aw[4];
#pragma unroll
    for (int cc = 0; cc < 4; ++cc)
      aw[cc] = *(const f16x8*)(wo16 + (cobase + cc * 16 + lo) * 512 + kc + hi * 8);
#pragma unroll
    for (int lc = 0; lc < 2; ++lc) {
      f16x8 bx = *(const f16x8*)(ab + (size_t)(lbase + lc * 16 + lo) * 512 + kc + hi * 8);
#pragma unroll
      for (int cc = 0; cc < 4; ++cc)
        acc[cc][lc] = __builtin_amdgcn_mfma_f32_16x16x32_f16(aw[cc], bx, acc[cc][lc], 0, 0, 0);
    }
  }
  float* ob = out + (size_t)b * C_ * L_;
#pragma unroll
  for (int cc = 0; cc < 4; ++cc)
#pragma unroll
    for (int lc = 0; lc < 2; ++lc) {
      int l = lbase + lc * 16 + lo;
#pragma unroll
      for (int i = 0; i < 4; ++i) {
        int co = cobase + cc * 16 + hi * 4 + i;
        ob[(size_t)co * L_ + l] = acc[cc][lc][i];
      }
    }
}

// ---------------------------------------------------------------- launch
extern "C" void kernel_launch(void* const* d_in, const int* in_sizes, int n_in,
                              void* d_out, int out_size, void* d_ws, size_t ws_size,
                              hipStream_t stream) {
  const float* x   = (const float*)d_in[0];
  const float* Wq  = (const float*)d_in[1];
  const float* Wkv = (const float*)d_in[2];
  const float* Wo  = (const float*)d_in[3];
  char* ws = (char*)d_ws;
  float2* sc  = (float2*)(ws + WS_SC);
  f16* wqkv   = (f16*)(ws + WS_WQKV);
  f16* wo16   = (f16*)(ws + WS_WO);
  f16* Qb     = (f16*)(ws + WS_Q);
  f16* Kb     = (f16*)(ws + WS_K);
  f16* Vtb    = (f16*)(ws + WS_VT);
  f16* attb   = (f16*)(ws + WS_ATT);
  float* opb  = (float*)(ws + WS_OP);
  float* lsb  = (float*)(ws + WS_LS);

  prep_kernel<<<1024, 256, 0, stream>>>(Wq, Wkv, Wo, wqkv, wo16, sc);
  qkv_kernel<<<768, 256, 0, stream>>>(x, wqkv, sc, Qb, Kb, Vtb);
  if (ws_size >= (size_t)WS_END) {
    attn_kernel<true><<<1024, 512, 0, stream>>>(Qb, Kb, Vtb, attb, opb, lsb);
    combine_kernel<<<4096, 256, 0, stream>>>(opb, lsb, attb);
  } else {
    attn_kernel<false><<<512, 512, 0, stream>>>(Qb, Kb, Vtb, attb, opb, lsb);
  }
  oproj_kernel<<<512, 256, 0, stream>>>(attb, wo16, (float*)d_out);
}

// Round 11
// 162.925 us; speedup vs baseline: 1.4334x; 1.0700x over previous
//
#include <hip/hip_runtime.h>

using f16   = _Float16;
using f16x2 = __attribute__((ext_vector_type(2))) f16;
using f16x4 = __attribute__((ext_vector_type(4))) f16;
using f16x8 = __attribute__((ext_vector_type(8))) f16;
using f32x4 = __attribute__((ext_vector_type(4))) float;

#define L_ 4096
#define C_ 512

static __device__ __forceinline__ float fast_exp2(float x) {
#if __has_builtin(__builtin_amdgcn_exp2f)
  return __builtin_amdgcn_exp2f(x);
#else
  float r; asm("v_exp_f32 %0, %1" : "=v"(r) : "v"(x)); return r;
#endif
}

// packed f32->f16 (RTZ) convert; bit-cast __fp16 vec -> _Float16 vec
static __device__ __forceinline__ f16x2 pk2(float a, float b) {
  return __builtin_bit_cast(f16x2, __builtin_amdgcn_cvt_pkrtz(a, b));
}

// workspace layout (bytes), all offsets 256-aligned
#define WS_SC    0u          // float2[4096*16]   sin/cos table      524288
#define WS_WQKV  524288u     // f16[768*512]                         786432
#define WS_WO    1310720u    // f16[512*512]                         524288
#define WS_Q     1835008u    // f16[2][8][4096][64]                  8388608
#define WS_K     10223616u   // f16[2][2][4096][64]                  2097152
#define WS_VT    12320768u   // f16[2][2][64][4096]  (transposed V)  2097152
#define WS_ATT   14417920u   // f16[2][4096][512]                    8388608
#define WS_OP    22806528u   // f32[2][2][8][4096][64] O partials    33554432
#define WS_LS    56360960u   // f32[2][2][8][4096]    lsum partials  524288
#define WS_END   56885248u

// ---------------------------------------------------------------- prep
__global__ __launch_bounds__(256) void prep_kernel(
    const float* __restrict__ Wq, const float* __restrict__ Wkv,
    const float* __restrict__ Wo,
    f16* __restrict__ wqkv, f16* __restrict__ wo16, float2* __restrict__ sc) {
  int t = blockIdx.x * 256 + threadIdx.x;
  if (t < 98304) {                 // 768*512 f16, 4 per thread
    int idx = t * 4;
    float4 v = (idx < 262144) ? *(const float4*)(Wq + idx)
                              : *(const float4*)(Wkv + (idx - 262144));
    f16x4 o = {(f16)v.x, (f16)v.y, (f16)v.z, (f16)v.w};
    *(f16x4*)(wqkv + idx) = o;
  } else if (t < 163840) {         // 512*512 f16
    int idx = (t - 98304) * 4;
    float4 v = *(const float4*)(Wo + idx);
    f16x4 o = {(f16)v.x, (f16)v.y, (f16)v.z, (f16)v.w};
    *(f16x4*)(wo16 + idx) = o;
  } else if (t < 229376) {         // 4096*16 sin/cos entries
    int e = t - 163840;
    int l = e >> 4, p = e & 15;
    float invf = exp2f(-(float)p * (13.287712379549449f / 16.0f));
    float ang = (float)l * invf;
    sc[e] = make_float2(sinf(ang), cosf(ang));
  }
}

// ---------------------------------------------------------------- QKV + RoPE
__global__ __launch_bounds__(256) void qkv_kernel(
    const float* __restrict__ x, const f16* __restrict__ wqkv,
    const float2* __restrict__ sc,
    f16* __restrict__ Qo, f16* __restrict__ Ko, f16* __restrict__ Vto) {
  int bid = blockIdx.x;
  int b   = bid / 384;
  int rem = bid % 384;
  int ot  = rem >> 7;       // 0..2
  int lt  = rem & 127;      // 0..127
  int wave = threadIdx.x >> 6, lane = threadIdx.x & 63;
  int lo = lane & 15, hi = lane >> 4;
  int obase = ot * 256 + wave * 64;
  int lbase = lt * 32;
  const float* xb = x + (size_t)b * C_ * L_;

  f32x4 acc[4][2] = {};
  for (int kc = 0; kc < 512; kc += 32) {
    f16x8 aw[4];
#pragma unroll
    for (int oc = 0; oc < 4; ++oc)
      aw[oc] = *(const f16x8*)(wqkv + (obase + oc * 16 + lo) * 512 + kc + hi * 8);
#pragma unroll
    for (int lc = 0; lc < 2; ++lc) {
      f16x8 bx;
#pragma unroll
      for (int i = 0; i < 8; ++i)
        bx[i] = (f16)xb[(size_t)(kc + hi * 8 + i) * L_ + lbase + lc * 16 + lo];
#pragma unroll
      for (int oc = 0; oc < 4; ++oc)
        acc[oc][lc] = __builtin_amdgcn_mfma_f32_16x16x32_f16(aw[oc], bx, acc[oc][lc], 0, 0, 0);
    }
  }

  bool is_q = obase < 512;
  int  og   = obase - 512;
  int  kvh  = is_q ? 0 : (og >> 7);
  bool is_v = (!is_q) && ((og & 127) == 64);
  int  h    = obase >> 6;
  const float QSCALE = 0.125f * 1.44269504088896340736f;

#pragma unroll
  for (int oc = 0; oc < 4; ++oc) {
#pragma unroll
    for (int lc = 0; lc < 2; ++lc) {
      f32x4 v = acc[oc][lc];
      int l = lbase + lc * 16 + lo;
      int d = oc * 16 + hi * 4;
      if (!is_v && oc < 2) {           // rotary on d<32 for q and k
        int p0 = d >> 1;
        float2 s0 = sc[l * 16 + p0];
        float2 s1 = sc[l * 16 + p0 + 1];
        float a0 = v[0], a1 = v[1], a2 = v[2], a3 = v[3];
        v[0] = a0 * s0.y - a1 * s0.x;
        v[1] = a1 * s0.y + a0 * s0.x;
        v[2] = a2 * s1.y - a3 * s1.x;
        v[3] = a3 * s1.y + a2 * s1.x;
      }
      if (is_q) {
        f16x4 st = {(f16)(v[0] * QSCALE), (f16)(v[1] * QSCALE),
                    (f16)(v[2] * QSCALE), (f16)(v[3] * QSCALE)};
        *(f16x4*)(Qo + (((size_t)b * 8 + h) * L_ + l) * 64 + d) = st;
      } else if (!is_v) {
        f16x4 st = {(f16)v[0], (f16)v[1], (f16)v[2], (f16)v[3]};
        *(f16x4*)(Ko + (((size_t)b * 2 + kvh) * L_ + l) * 64 + d) = st;
      } else {
#pragma unroll
        for (int i = 0; i < 4; ++i)
          Vto[(((size_t)b * 2 + kvh) * 64 + d + i) * L_ + l] = (f16)v[i];
      }
    }
  }
}

// ---------------------------------------------------------------- flash attention
// Block = 8 waves x 32 q rows = 256 q rows, 512 threads.
// (32 q/wave: the K/V LDS tiles are read once per wave per chunk — doubling q
//  per wave halves LDS read traffic, which round-10 showed to be the roofline.)
// KSPLIT: grid 512, each block does 2048 keys (32 chunks), writes unnormalized
// O-partial (f32) + lsum to ws; combine kernel adds halves & normalizes.
// NOTE: plain __launch_bounds__(512) — (512,8) capped VGPR at 32 and spilled
// ~500MB to scratch (round-9 post-mortem).
template <bool KSPLIT>
__global__ __launch_bounds__(512) void attn_kernel(
    const f16* __restrict__ Qi, const f16* __restrict__ Ki,
    const f16* __restrict__ Vti, f16* __restrict__ att,
    float* __restrict__ opart, float* __restrict__ lsews) {
  __shared__ __align__(16) char smem[2][16384];
  int bid  = blockIdx.x;
  int half = KSPLIT ? (bid >> 8) : 0;
  int rem9 = KSPLIT ? (bid & 255) : bid;
  int b   = rem9 >> 7;
  int rem = rem9 & 127;
  int h   = rem >> 4;
  int qt  = rem & 15;
  int tid  = threadIdx.x;
  int wave = tid >> 6, lane = tid & 63;
  int lo = lane & 15, hi = lane >> 4;
  int kvh = h >> 2;
  const f16*  Qp   = Qi + ((size_t)(b * 8 + h) * L_) * 64;
  const char* Ksrc = (const char*)(Ki  + ((size_t)(b * 2 + kvh)) * L_ * 64)
                     + (size_t)half * 262144;                     // +2048 keys
  const char* Vsrc = (const char*)(Vti + ((size_t)(b * 2 + kvh)) * 64 * L_)
                     + (size_t)half * 4096;                       // +2048 cols

  int lqb = qt * 256 + wave * 32;
  f16x8 qf[2][2];
#pragma unroll
  for (int qi = 0; qi < 2; ++qi)
#pragma unroll
    for (int hf = 0; hf < 2; ++hf)
      qf[qi][hf] = *(const f16x8*)(Qp + (size_t)(lqb + qi * 16 + lo) * 64 + hf * 32 + hi * 8);

  // staging: 512 threads, one 16B K-chunk + one 16B V-chunk each (8KB tiles)
  int c0 = tid;
  int r0 = c0 >> 3, m0 = c0 & 7;
  int cb0 = m0 << 4;
  int dstK0 = r0 * 128 + (cb0 ^ ((r0 & 7) << 4));
  int ca0 = (m0 >> 2) * 64 + ((2 * m0) & 3) * 16 + ((m0 >> 1) & 1) * 8;
  int dstV0a = r0 * 128 + (ca0 ^ ((r0 & 7) << 4));
  int dstV0b = r0 * 128 + ((ca0 + 16) ^ ((r0 & 7) << 4));

  f16x8 sK0, sV0;
#define STAGE_LOAD(t) do {                                            \
    sK0 = *(const f16x8*)(Ksrc + (size_t)(t) * 8192 + c0 * 16);       \
    sV0 = *(const f16x8*)(Vsrc + (size_t)r0 * 8192 + (t) * 128 + cb0);\
  } while (0)
#define STAGE_WRITE(base_) do {                                       \
    char* kb_ = (char*)(base_);                                       \
    *(f16x8*)(kb_ + dstK0) = sK0;                                     \
    *(f16x4*)(kb_ + 8192 + dstV0a) = __builtin_shufflevector(sV0, sV0, 0, 1, 2, 3); \
    *(f16x4*)(kb_ + 8192 + dstV0b) = __builtin_shufflevector(sV0, sV0, 4, 5, 6, 7); \
  } while (0)

  f32x4 oacc[4][2] = {};
  f32x4 lse[2] = {};                        // ones-row MFMA accumulator
  const f16x4 ones = {(f16)1.f, (f16)1.f, (f16)1.f, (f16)1.f};
  int swz = (lo & 7) << 4;

#define COMPUTE(buf_) do {                                                          \
    const char* kb = (const char*)(buf_);                                           \
    const char* vb = kb + 8192;                                                     \
    f32x4 s[4][2] = {};                                                             \
    __builtin_amdgcn_s_setprio(1);                                                  \
    _Pragma("unroll")                                                               \
    for (int j = 0; j < 4; ++j) {                                                   \
      f16x8 ka0 = *(const f16x8*)(kb + (j * 16 + lo) * 128 + ((hi * 16) ^ swz));    \
      f16x8 ka1 = *(const f16x8*)(kb + (j * 16 + lo) * 128 + ((64 + hi * 16) ^ swz));\
      _Pragma("unroll")                                                             \
      for (int qi = 0; qi < 2; ++qi) {                                              \
        s[j][qi] = __builtin_amdgcn_mfma_f32_16x16x32_f16(ka0, qf[qi][0], s[j][qi], 0, 0, 0); \
        s[j][qi] = __builtin_amdgcn_mfma_f32_16x16x32_f16(ka1, qf[qi][1], s[j][qi], 0, 0, 0); \
      }                                                                             \
    }                                                                               \
    __builtin_amdgcn_s_setprio(0);                                                  \
    f16x4 pf[4][2];                                                                 \
    _Pragma("unroll")                                                               \
    for (int qi = 0; qi < 2; ++qi)                                                  \
      _Pragma("unroll")                                                             \
      for (int j = 0; j < 4; ++j) {                                                 \
        f16x2 p01 = pk2(fast_exp2(s[j][qi][0]), fast_exp2(s[j][qi][1]));            \
        f16x2 p23 = pk2(fast_exp2(s[j][qi][2]), fast_exp2(s[j][qi][3]));            \
        pf[j][qi] = __builtin_shufflevector(p01, p23, 0, 1, 2, 3);                  \
      }                                                                             \
    __builtin_amdgcn_s_setprio(1);                                                  \
    _Pragma("unroll")                                                               \
    for (int dc = 0; dc < 4; ++dc) {                                                \
      _Pragma("unroll")                                                             \
      for (int jp = 0; jp < 2; ++jp) {                                              \
        f16x8 vv = *(const f16x8*)(vb + (dc * 16 + lo) * 128 + ((jp * 64 + hi * 16) ^ swz)); \
        f16x4 va0 = __builtin_shufflevector(vv, vv, 0, 1, 2, 3);                    \
        f16x4 va1 = __builtin_shufflevector(vv, vv, 4, 5, 6, 7);                    \
        oacc[dc][0] = __builtin_amdgcn_mfma_f32_16x16x16f16(va0, pf[2 * jp][0], oacc[dc][0], 0, 0, 0); \
        oacc[dc][1] = __builtin_amdgcn_mfma_f32_16x16x16f16(va0, pf[2 * jp][1], oacc[dc][1], 0, 0, 0); \
        oacc[dc][0] = __builtin_amdgcn_mfma_f32_16x16x16f16(va1, pf[2 * jp + 1][0], oacc[dc][0], 0, 0, 0); \
        oacc[dc][1] = __builtin_amdgcn_mfma_f32_16x16x16f16(va1, pf[2 * jp + 1][1], oacc[dc][1], 0, 0, 0); \
      }                                                                             \
    }                                                                               \
    _Pragma("unroll")                                                               \
    for (int j = 0; j < 4; ++j) {                                                   \
      lse[0] = __builtin_amdgcn_mfma_f32_16x16x16f16(ones, pf[j][0], lse[0], 0, 0, 0); \
      lse[1] = __builtin_amdgcn_mfma_f32_16x16x16f16(ones, pf[j][1], lse[1], 0, 0, 0); \
    }                                                                               \
    __builtin_amdgcn_s_setprio(0);                                                  \
  } while (0)

  const int NT = KSPLIT ? 32 : 64;
  STAGE_LOAD(0);
  STAGE_WRITE(smem[0]);
  __syncthreads();

  for (int t = 0; t < NT; t += 2) {
    STAGE_LOAD(t + 1);                 // t+1 <= NT-1 always valid
    COMPUTE(smem[0]);
    STAGE_WRITE(smem[1]);
    __syncthreads();
    if (t + 2 < NT) STAGE_LOAD(t + 2);
    COMPUTE(smem[1]);
    if (t + 2 < NT) STAGE_WRITE(smem[0]);
    __syncthreads();
  }

#pragma unroll
  for (int qi = 0; qi < 2; ++qi) {
    int lq = lqb + qi * 16 + lo;
    if constexpr (KSPLIT) {
      size_t obase = ((((size_t)half * 2 + b) * 8 + h) * L_ + lq) * 64;
#pragma unroll
      for (int dc = 0; dc < 4; ++dc)
        *(f32x4*)(opart + obase + dc * 16 + hi * 4) = oacc[dc][qi];
      if (hi == 0)
        lsews[(((size_t)half * 2 + b) * 8 + h) * L_ + lq] = lse[qi][0];
    } else {
      float inv = 1.f / lse[qi][0];
#pragma unroll
      for (int dc = 0; dc < 4; ++dc) {
        f16x4 st;
#pragma unroll
        for (int i = 0; i < 4; ++i) st[i] = (f16)(oacc[dc][qi][i] * inv);
        *(f16x4*)(att + ((size_t)b * L_ + lq) * 512 + h * 64 + dc * 16 + hi * 4) = st;
      }
    }
  }
#undef STAGE_LOAD
#undef STAGE_WRITE
#undef COMPUTE
}

// ---------------------------------------------------------------- combine halves
__global__ __launch_bounds__(256) void combine_kernel(
    const float* __restrict__ opart, const float* __restrict__ lsews,
    f16* __restrict__ att) {
  int t = blockIdx.x * 256 + threadIdx.x;     // 2*8*4096*16 = 1048576 threads
  int d4 = t & 15;
  int lq = (t >> 4) & 4095;
  int h  = (t >> 16) & 7;
  int b  = t >> 19;
  const size_t HS = (size_t)2 * 8 * 4096 * 64;     // opart half stride (floats)
  size_t base  = (((size_t)b * 8 + h) * 4096 + lq) * 64 + d4 * 4;
  size_t lbase = ((size_t)b * 8 + h) * 4096 + lq;
  f32x4 o0 = *(const f32x4*)(opart + base);
  f32x4 o1 = *(const f32x4*)(opart + HS + base);
  float inv = 1.f / (lsews[lbase] + lsews[(size_t)2 * 8 * 4096 + lbase]);
  f16x4 st;
#pragma unroll
  for (int i = 0; i < 4; ++i) st[i] = (f16)((o0[i] + o1[i]) * inv);
  *(f16x4*)(att + ((size_t)b * 4096 + lq) * 512 + h * 64 + d4 * 4) = st;
}

// ---------------------------------------------------------------- output projection
__global__ __launch_bounds__(256) void oproj_kernel(
    const f16* __restrict__ att, const f16* __restrict__ wo16,
    float* __restrict__ out) {
  int bid = blockIdx.x;
  int b   = bid / 256;
  int rem = bid % 256;
  int ct  = rem >> 7;
  int lt  = rem & 127;
  int wave = threadIdx.x >> 6, lane = threadIdx.x & 63;
  int lo = lane & 15, hi = lane >> 4;
  int cobase = ct * 256 + wave * 64;
  int lbase  = lt * 32;
  const f16* ab = att + (size_t)b * L_ * 512;

  f32x4 acc[4][2] = {};
  for (int kc = 0; kc < 512; kc += 32) {
    f16x8 aw[4];
#pragma unroll
    for (int cc = 0; cc < 4; ++cc)
      aw[cc] = *(const f16x8*)(wo16 + (cobase + cc * 16 + lo) * 512 + kc + hi * 8);
#pragma unroll
    for (int lc = 0; lc < 2; ++lc) {
      f16x8 bx = *(const f16x8*)(ab + (size_t)(lbase + lc * 16 + lo) * 512 + kc + hi * 8);
#pragma unroll
      for (int cc = 0; cc < 4; ++cc)
        acc[cc][lc] = __builtin_amdgcn_mfma_f32_16x16x32_f16(aw[cc], bx, acc[cc][lc], 0, 0, 0);
    }
  }
  float* ob = out + (size_t)b * C_ * L_;
#pragma unroll
  for (int cc = 0; cc < 4; ++cc)
#pragma unroll
    for (int lc = 0; lc < 2; ++lc) {
      int l = lbase + lc * 16 + lo;
#pragma unroll
      for (int i = 0; i < 4; ++i) {
        int co = cobase + cc * 16 + hi * 4 + i;
        ob[(size_t)co * L_ + l] = acc[cc][lc][i];
      }
    }
}

// ---------------------------------------------------------------- launch
extern "C" void kernel_launch(void* const* d_in, const int* in_sizes, int n_in,
                              void* d_out, int out_size, void* d_ws, size_t ws_size,
                              hipStream_t stream) {
  const float* x   = (const float*)d_in[0];
  const float* Wq  = (const float*)d_in[1];
  const float* Wkv = (const float*)d_in[2];
  const float* Wo  = (const float*)d_in[3];
  char* ws = (char*)d_ws;
  float2* sc  = (float2*)(ws + WS_SC);
  f16* wqkv   = (f16*)(ws + WS_WQKV);
  f16* wo16   = (f16*)(ws + WS_WO);
  f16* Qb     = (f16*)(ws + WS_Q);
  f16* Kb     = (f16*)(ws + WS_K);
  f16* Vtb    = (f16*)(ws + WS_VT);
  f16* attb   = (f16*)(ws + WS_ATT);
  float* opb  = (float*)(ws + WS_OP);
  float* lsb  = (float*)(ws + WS_LS);

  prep_kernel<<<1024, 256, 0, stream>>>(Wq, Wkv, Wo, wqkv, wo16, sc);
  qkv_kernel<<<768, 256, 0, stream>>>(x, wqkv, sc, Qb, Kb, Vtb);
  if (ws_size >= (size_t)WS_END) {
    attn_kernel<true><<<512, 512, 0, stream>>>(Qb, Kb, Vtb, attb, opb, lsb);
    combine_kernel<<<4096, 256, 0, stream>>>(opb, lsb, attb);
  } else {
    attn_kernel<false><<<256, 512, 0, stream>>>(Qb, Kb, Vtb, attb, opb, lsb);
  }
  oproj_kernel<<<512, 256, 0, stream>>>(attb, wo16, (float*)d_out);
}